// Round 2
// baseline (234558.105 us; speedup 1.0000x reference)
//
#include <hip/hip_runtime.h>
#include <math.h>

#define BATCH 8
#define SEQ   4096
#define DIM   512

// ---------------------------------------------------------------------------
// Projection GEMM: Out[M, 512] = X[M, 512] @ W[512, 512], fp32.
// BM=64, BN=64, BK=16, 256 threads, 4x4 micro-tile per thread.
// ---------------------------------------------------------------------------
__global__ __launch_bounds__(256) void proj_kernel(
    const float* __restrict__ X, const float* __restrict__ W,
    float* __restrict__ Out) {
  __shared__ float Xs[64][17];   // +1 pad breaks pow2 stride
  __shared__ float Ws[16][68];   // +4 pad
  const int tid = threadIdx.x;
  const int tx = tid & 15, ty = tid >> 4;
  const int rowBase = blockIdx.y * 64, colBase = blockIdx.x * 64;
  float acc[4][4] = {};
  for (int k0 = 0; k0 < DIM; k0 += 16) {
    for (int idx = tid; idx < 64 * 16; idx += 256) {
      int r = idx >> 4, c = idx & 15;
      Xs[r][c] = X[(size_t)(rowBase + r) * DIM + k0 + c];
    }
    for (int idx = tid; idx < 16 * 64; idx += 256) {
      int r = idx >> 6, c = idx & 63;
      Ws[r][c] = W[(size_t)(k0 + r) * DIM + colBase + c];
    }
    __syncthreads();
#pragma unroll
    for (int k = 0; k < 16; ++k) {
      float xv[4], wv[4];
#pragma unroll
      for (int i = 0; i < 4; ++i) xv[i] = Xs[ty * 4 + i][k];
#pragma unroll
      for (int j = 0; j < 4; ++j) wv[j] = Ws[k][tx * 4 + j];
#pragma unroll
      for (int i = 0; i < 4; ++i)
#pragma unroll
        for (int j = 0; j < 4; ++j) acc[i][j] += xv[i] * wv[j];
    }
    __syncthreads();
  }
#pragma unroll
  for (int i = 0; i < 4; ++i)
#pragma unroll
    for (int j = 0; j < 4; ++j)
      Out[(size_t)(rowBase + ty * 4 + i) * DIM + colBase + tx * 4 + j] =
          acc[i][j];
}

// ---------------------------------------------------------------------------
// Flash-style attention, fp32, online softmax.
// Block = 256 threads, TQ=16 query rows, key tiles of TK=64, D chunked by 64.
// One LDS staging buffer reused for K (S-stage) and x/V (PV-stage).
// Thread layout: ti = tid/16 (query row), tj = tid%16.
//   S-stage:  thread owns S[ti][tj + 16u], u=0..3
//   PV-stage: thread owns O[ti][c*64 + tj + 16u], c=0..7, u=0..3
// ---------------------------------------------------------------------------
__global__ __launch_bounds__(256) void attn_kernel(
    const float* __restrict__ Q, const float* __restrict__ K,
    const float* __restrict__ X, float* __restrict__ Out) {
  constexpr int TQ = 16, TK = 64, DCH = 64;
  __shared__ float Qs[TQ][DIM + 4];   // 33024 B
  __shared__ float Ks[TK][DCH + 4];   // 17408 B
  __shared__ float Ps[TQ][TK + 1];    // 4160 B
  __shared__ float red_s[TQ][16 + 1]; // row-reduction scratch
  __shared__ float m_s[TQ], l_s[TQ], alpha_s[TQ];

  const int tid = threadIdx.x;
  const int b  = blockIdx.y;
  const int q0 = blockIdx.x * TQ;
  const int ti = tid >> 4, tj = tid & 15;

  // Load the Q tile once (vectorized float4).
  const float* Qb = Q + ((size_t)b * SEQ + q0) * DIM;
  for (int idx = tid; idx < TQ * (DIM / 4); idx += 256) {
    int r = idx >> 7, c4 = idx & 127;  // DIM/4 = 128 float4 per row
    float4 v = *(const float4*)(Qb + (size_t)r * DIM + c4 * 4);
    *(float4*)&Qs[r][c4 * 4] = v;
  }
  if (tid < TQ) { m_s[tid] = -3.0e38f; l_s[tid] = 0.0f; }

  float O[8][4];
#pragma unroll
  for (int c = 0; c < 8; ++c)
#pragma unroll
    for (int u = 0; u < 4; ++u) O[c][u] = 0.0f;
  __syncthreads();

  for (int k0 = 0; k0 < SEQ; k0 += TK) {
    // ---------------- S = Q K^T for this key tile ----------------
    float s[4] = {0.f, 0.f, 0.f, 0.f};
    const float* Kb = K + ((size_t)b * SEQ + k0) * DIM;
    for (int c0 = 0; c0 < DIM; c0 += DCH) {
      __syncthreads();  // staging buffer free from previous use
      for (int idx = tid; idx < TK * (DCH / 4); idx += 256) {
        int r = idx >> 4, c4 = idx & 15;  // DCH/4 = 16 float4 per row
        float4 v = *(const float4*)(Kb + (size_t)r * DIM + c0 + c4 * 4);
        *(float4*)&Ks[r][c4 * 4] = v;
      }
      __syncthreads();
#pragma unroll 8
      for (int kk = 0; kk < DCH; ++kk) {
        float q = Qs[ti][c0 + kk];
        s[0] += q * Ks[tj][kk];
        s[1] += q * Ks[tj + 16][kk];
        s[2] += q * Ks[tj + 32][kk];
        s[3] += q * Ks[tj + 48][kk];
      }
    }
    const float scale = 0.04419417382415922f;  // 1/sqrt(512)
    s[0] *= scale; s[1] *= scale; s[2] *= scale; s[3] *= scale;
    Ps[ti][tj]      = s[0];
    Ps[ti][tj + 16] = s[1];
    Ps[ti][tj + 32] = s[2];
    Ps[ti][tj + 48] = s[3];

    // ---- parallel row max: each thread reduces its 4 values ----
    float tmax4 = fmaxf(fmaxf(s[0], s[1]), fmaxf(s[2], s[3]));
    red_s[ti][tj] = tmax4;
    __syncthreads();
    if (tid < TQ) {
      const int r = tid;
      float m_old = m_s[r];
      float tm = m_old;
#pragma unroll
      for (int j = 0; j < 16; ++j) tm = fmaxf(tm, red_s[r][j]);
      m_s[r] = tm;
      alpha_s[r] = __expf(m_old - tm);
    }
    __syncthreads();

    // ---- parallel exp + partial sums ----
    const float tm = m_s[ti];
    float p0 = __expf(s[0] - tm);
    float p1 = __expf(s[1] - tm);
    float p2 = __expf(s[2] - tm);
    float p3 = __expf(s[3] - tm);
    Ps[ti][tj]      = p0;
    Ps[ti][tj + 16] = p1;
    Ps[ti][tj + 32] = p2;
    Ps[ti][tj + 48] = p3;
    red_s[ti][tj] = (p0 + p1) + (p2 + p3);
    __syncthreads();
    if (tid < TQ) {
      const int r = tid;
      float ts = 0.0f;
#pragma unroll
      for (int j = 0; j < 16; ++j) ts += red_s[r][j];
      l_s[r] = l_s[r] * alpha_s[r] + ts;
    }
    __syncthreads();
    const float alpha = alpha_s[ti];

    // ---------------- O = O*alpha + P @ x[tile] ----------------
    const float* Xb = X + ((size_t)b * SEQ + k0) * DIM;
    for (int c = 0; c < 8; ++c) {
      __syncthreads();  // everyone done reading staging buffer
      for (int idx = tid; idx < TK * (DCH / 4); idx += 256) {
        int r = idx >> 4, c4 = idx & 15;
        float4 v = *(const float4*)(Xb + (size_t)r * DIM + c * DCH + c4 * 4);
        *(float4*)&Ks[r][c4 * 4] = v;
      }
      __syncthreads();
#pragma unroll
      for (int u = 0; u < 4; ++u) O[c][u] *= alpha;
      for (int j = 0; j < TK; ++j) {
        float p = Ps[ti][j];
#pragma unroll
        for (int u = 0; u < 4; ++u) O[c][u] += p * Ks[j][tj + 16 * u];
      }
    }
  }

  const float invl = 1.0f / l_s[ti];
  float* Ob = Out + ((size_t)b * SEQ + q0 + ti) * DIM;
#pragma unroll
  for (int c = 0; c < 8; ++c)
#pragma unroll
    for (int u = 0; u < 4; ++u)
      Ob[c * 64 + tj + 16 * u] = O[c][u] * invl;
}

// ---------------------------------------------------------------------------
extern "C" void kernel_launch(void* const* d_in, const int* in_sizes, int n_in,
                              void* d_out, int out_size, void* d_ws,
                              size_t ws_size, hipStream_t stream) {
  const float* x        = (const float*)d_in[0];  // [B, N, D]
  const float* rotation = (const float*)d_in[1];  // [D, D]
  const float* entangle = (const float*)d_in[2];  // [D, D]
  float* out = (float*)d_out;                     // [B, N, D]

  const size_t elems = (size_t)BATCH * SEQ * DIM;  // 16,777,216
  float* Qw = (float*)d_ws;          // 64 MB
  float* Kw = Qw + elems;            // 64 MB

  // Q = x @ rotation ; K = x @ entangle   (M = B*N = 32768 rows)
  dim3 pgrid(DIM / 64, (BATCH * SEQ) / 64, 1);  // (8, 512)
  proj_kernel<<<pgrid, 256, 0, stream>>>(x, rotation, Qw);
  proj_kernel<<<pgrid, 256, 0, stream>>>(x, entangle, Kw);

  // out = softmax(Q K^T / sqrt(D)) @ x
  dim3 agrid(SEQ / 16, BATCH, 1);  // (256, 8)
  attn_kernel<<<agrid, 256, 0, stream>>>(Qw, Kw, x, out);
}

// Round 3
// 3245.110 us; speedup vs baseline: 72.2805x; 72.2805x over previous
//
#include <hip/hip_runtime.h>

#define BATCH 8
#define SEQ   4096
#define DIM   512

typedef __attribute__((ext_vector_type(8))) short bf16x8;
typedef __attribute__((ext_vector_type(4))) float f32x4;

__device__ __forceinline__ unsigned short f2bf(float f) {
  unsigned int u = __float_as_uint(f);
  unsigned int r = (u + 0x7fffu + ((u >> 16) & 1u)) >> 16;
  return (unsigned short)r;
}
__device__ __forceinline__ float bf2f(unsigned short s) {
  return __uint_as_float(((unsigned int)s) << 16);
}

// ---------------------------------------------------------------------------
// Transpose + split weights: Wt[e][d] = W[d][e] * scale, as bf16 hi/lo.
// Scale (1/sqrt(512)) folded into rotation only.
// ---------------------------------------------------------------------------
__global__ __launch_bounds__(256) void wt_split_kernel(
    const float* __restrict__ rot, const float* __restrict__ ent,
    unsigned short* __restrict__ wrh, unsigned short* __restrict__ wrl,
    unsigned short* __restrict__ weh, unsigned short* __restrict__ wel) {
  const float scale = 0.04419417382415922f;  // 1/sqrt(512)
  int g = blockIdx.x * 256 + threadIdx.x;
  for (int idx = g; idx < 512 * 512; idx += 128 * 256) {
    int d = idx >> 9, e = idx & 511;
    size_t o = (size_t)e * 512 + d;
    float v = rot[idx] * scale;
    unsigned short h = f2bf(v);
    wrh[o] = h; wrl[o] = f2bf(v - bf2f(h));
    float v2 = ent[idx];
    unsigned short h2 = f2bf(v2);
    weh[o] = h2; wel[o] = f2bf(v2 - bf2f(h2));
  }
}

// ---------------------------------------------------------------------------
// Transpose + split x: Xt[b][d][n] = x[b][n][d], bf16 hi/lo (PV B-fragments).
// ---------------------------------------------------------------------------
__global__ __launch_bounds__(256) void xt_split_kernel(
    const float* __restrict__ X, unsigned short* __restrict__ Th,
    unsigned short* __restrict__ Tl) {
  __shared__ float T[64][65];
  const int b = blockIdx.z, n0 = blockIdx.x * 64, d0 = blockIdx.y * 64;
  const int tid = threadIdx.x;
  for (int idx = tid; idx < 4096; idx += 256) {
    int r = idx >> 6, c = idx & 63;
    T[r][c] = X[((size_t)(b * SEQ + n0 + r)) * DIM + d0 + c];
  }
  __syncthreads();
  for (int idx = tid; idx < 4096; idx += 256) {
    int r = idx >> 6, c = idx & 63;  // r: d, c: n
    float v = T[c][r];
    unsigned short h = f2bf(v);
    size_t o = ((size_t)(b * DIM + d0 + r)) * SEQ + n0 + c;
    Th[o] = h; Tl[o] = f2bf(v - bf2f(h));
  }
}

// ---------------------------------------------------------------------------
// Projection GEMM via bf16-split MFMA (3 terms): Out = X @ W, written as hi/lo.
// Block 64x64 tile, 4 waves, each wave 2x2 16x16 MFMA tiles.
// ---------------------------------------------------------------------------
__global__ __launch_bounds__(256, 2) void proj_mfma(
    const float* __restrict__ X, const unsigned short* __restrict__ Wh,
    const unsigned short* __restrict__ Wl,
    unsigned short* __restrict__ Oh, unsigned short* __restrict__ Ol) {
  const int tid = threadIdx.x;
  const int w = tid >> 6, lane = tid & 63, l15 = lane & 15, quad = lane >> 4;
  const int rowBase = blockIdx.y * 64 + (w & 1) * 32;
  const int colBase = blockIdx.x * 64 + (w >> 1) * 32;
  f32x4 acc[2][2] = {};
  const float* xp[2];
  const unsigned short *wh[2], *wl[2];
  xp[0] = X + (size_t)(rowBase + l15) * DIM + quad * 8;
  xp[1] = X + (size_t)(rowBase + 16 + l15) * DIM + quad * 8;
  wh[0] = Wh + (size_t)(colBase + l15) * DIM + quad * 8;
  wh[1] = Wh + (size_t)(colBase + 16 + l15) * DIM + quad * 8;
  wl[0] = Wl + (size_t)(colBase + l15) * DIM + quad * 8;
  wl[1] = Wl + (size_t)(colBase + 16 + l15) * DIM + quad * 8;
  for (int d0 = 0; d0 < DIM; d0 += 32) {
    bf16x8 ah[2], al[2], bh[2], bl[2];
#pragma unroll
    for (int mi = 0; mi < 2; ++mi) {
      const float* p = xp[mi] + d0;
#pragma unroll
      for (int e = 0; e < 8; ++e) {
        float v = p[e];
        unsigned short h = f2bf(v);
        ah[mi][e] = (short)h;
        al[mi][e] = (short)f2bf(v - bf2f(h));
      }
    }
#pragma unroll
    for (int ni = 0; ni < 2; ++ni) {
      bh[ni] = *(const bf16x8*)(wh[ni] + d0);
      bl[ni] = *(const bf16x8*)(wl[ni] + d0);
    }
#pragma unroll
    for (int mi = 0; mi < 2; ++mi)
#pragma unroll
      for (int ni = 0; ni < 2; ++ni) {
        acc[mi][ni] = __builtin_amdgcn_mfma_f32_16x16x32_bf16(ah[mi], bh[ni], acc[mi][ni], 0, 0, 0);
        acc[mi][ni] = __builtin_amdgcn_mfma_f32_16x16x32_bf16(ah[mi], bl[ni], acc[mi][ni], 0, 0, 0);
        acc[mi][ni] = __builtin_amdgcn_mfma_f32_16x16x32_bf16(al[mi], bh[ni], acc[mi][ni], 0, 0, 0);
      }
  }
#pragma unroll
  for (int mi = 0; mi < 2; ++mi)
#pragma unroll
    for (int ni = 0; ni < 2; ++ni)
#pragma unroll
      for (int r = 0; r < 4; ++r) {
        int row = rowBase + mi * 16 + quad * 4 + r;
        int col = colBase + ni * 16 + l15;
        float v = acc[mi][ni][r];
        unsigned short h = f2bf(v);
        size_t o = (size_t)row * DIM + col;
        Oh[o] = h; Ol[o] = f2bf(v - bf2f(h));
      }
}

// ---------------------------------------------------------------------------
// Flash attention, bf16-split MFMA. BQ=64, BK=64, 4 waves.
// S-stage: wave w -> q-subs {2(w&1),+1}, k-subs {2(w>>1),+1}, frags from global.
// P: exp'd in C-layout regs, split to bf16 hi/lo in LDS, re-read as A-frags.
// PV: wave w owns d-slice [w*128, w*128+128), X frags from global (Xt).
// ---------------------------------------------------------------------------
__global__ __launch_bounds__(256, 2) void attn_mfma(
    const unsigned short* __restrict__ Qh, const unsigned short* __restrict__ Ql,
    const unsigned short* __restrict__ Kh, const unsigned short* __restrict__ Kl,
    const unsigned short* __restrict__ Xth, const unsigned short* __restrict__ Xtl,
    float* __restrict__ out) {
  __shared__ unsigned short PsH[64][72];   // pad 72: 144B rows, 16B-aligned
  __shared__ unsigned short PsL[64][72];
  __shared__ float red1[64][2], red2[64][2];
  __shared__ float m_s[64], l_s[64], al_s[64];

  const int tid = threadIdx.x;
  const int w = tid >> 6, lane = tid & 63, l15 = lane & 15, quad = lane >> 4;
  const int b = blockIdx.y, q0 = blockIdx.x * 64;
  const int qsp = (w & 1) * 2, ksp = (w >> 1) * 2;
  const int dbase = w * 128;

  if (tid < 64) { m_s[tid] = -3.0e38f; l_s[tid] = 0.0f; }
  __syncthreads();

  f32x4 Of[4][8] = {};

  const size_t qoff0 = ((size_t)(b * SEQ + q0 + (qsp + 0) * 16 + l15)) * DIM + quad * 8;
  const size_t qoff1 = ((size_t)(b * SEQ + q0 + (qsp + 1) * 16 + l15)) * DIM + quad * 8;

  for (int k0 = 0; k0 < SEQ; k0 += 64) {
    // ----------------- S = Q K^T (3-term split) -----------------
    f32x4 sa[2][2] = {};
    const size_t koff0 = ((size_t)(b * SEQ + k0 + (ksp + 0) * 16 + l15)) * DIM + quad * 8;
    const size_t koff1 = ((size_t)(b * SEQ + k0 + (ksp + 1) * 16 + l15)) * DIM + quad * 8;
#pragma unroll 2
    for (int d0 = 0; d0 < DIM; d0 += 32) {
      bf16x8 a0h = *(const bf16x8*)(Qh + qoff0 + d0);
      bf16x8 a0l = *(const bf16x8*)(Ql + qoff0 + d0);
      bf16x8 a1h = *(const bf16x8*)(Qh + qoff1 + d0);
      bf16x8 a1l = *(const bf16x8*)(Ql + qoff1 + d0);
      bf16x8 b0h = *(const bf16x8*)(Kh + koff0 + d0);
      bf16x8 b0l = *(const bf16x8*)(Kl + koff0 + d0);
      bf16x8 b1h = *(const bf16x8*)(Kh + koff1 + d0);
      bf16x8 b1l = *(const bf16x8*)(Kl + koff1 + d0);
      sa[0][0] = __builtin_amdgcn_mfma_f32_16x16x32_bf16(a0h, b0h, sa[0][0], 0, 0, 0);
      sa[0][0] = __builtin_amdgcn_mfma_f32_16x16x32_bf16(a0h, b0l, sa[0][0], 0, 0, 0);
      sa[0][0] = __builtin_amdgcn_mfma_f32_16x16x32_bf16(a0l, b0h, sa[0][0], 0, 0, 0);
      sa[0][1] = __builtin_amdgcn_mfma_f32_16x16x32_bf16(a0h, b1h, sa[0][1], 0, 0, 0);
      sa[0][1] = __builtin_amdgcn_mfma_f32_16x16x32_bf16(a0h, b1l, sa[0][1], 0, 0, 0);
      sa[0][1] = __builtin_amdgcn_mfma_f32_16x16x32_bf16(a0l, b1h, sa[0][1], 0, 0, 0);
      sa[1][0] = __builtin_amdgcn_mfma_f32_16x16x32_bf16(a1h, b0h, sa[1][0], 0, 0, 0);
      sa[1][0] = __builtin_amdgcn_mfma_f32_16x16x32_bf16(a1h, b0l, sa[1][0], 0, 0, 0);
      sa[1][0] = __builtin_amdgcn_mfma_f32_16x16x32_bf16(a1l, b0h, sa[1][0], 0, 0, 0);
      sa[1][1] = __builtin_amdgcn_mfma_f32_16x16x32_bf16(a1h, b1h, sa[1][1], 0, 0, 0);
      sa[1][1] = __builtin_amdgcn_mfma_f32_16x16x32_bf16(a1h, b1l, sa[1][1], 0, 0, 0);
      sa[1][1] = __builtin_amdgcn_mfma_f32_16x16x32_bf16(a1l, b1h, sa[1][1], 0, 0, 0);
    }

    // ----------------- row-max partials -----------------
    float pm[2][4];
#pragma unroll
    for (int qi = 0; qi < 2; ++qi)
#pragma unroll
      for (int r = 0; r < 4; ++r) {
        float v = fmaxf(sa[qi][0][r], sa[qi][1][r]);
#pragma unroll
        for (int off = 1; off < 16; off <<= 1)
          v = fmaxf(v, __shfl_xor(v, off, 64));
        pm[qi][r] = v;
      }
    if (l15 == 0) {
#pragma unroll
      for (int qi = 0; qi < 2; ++qi)
#pragma unroll
        for (int r = 0; r < 4; ++r)
          red1[(qsp + qi) * 16 + quad * 4 + r][w >> 1] = pm[qi][r];
    }
    __syncthreads();  // B1
    if (tid < 64) {
      float mo = m_s[tid];
      float mn = fmaxf(mo, fmaxf(red1[tid][0], red1[tid][1]));
      m_s[tid] = mn;
      al_s[tid] = __expf(mo - mn);
    }
    __syncthreads();  // B2

    // ----------------- exp + split-P to LDS + row sums -----------------
#pragma unroll
    for (int qi = 0; qi < 2; ++qi)
#pragma unroll
      for (int r = 0; r < 4; ++r) {
        const int row = (qsp + qi) * 16 + quad * 4 + r;
        const float m = m_s[row];
        float p0 = __expf(sa[qi][0][r] - m);
        float p1 = __expf(sa[qi][1][r] - m);
        unsigned short h0 = f2bf(p0), h1 = f2bf(p1);
        PsH[row][ksp * 16 + l15] = h0;
        PsL[row][ksp * 16 + l15] = f2bf(p0 - bf2f(h0));
        PsH[row][ksp * 16 + 16 + l15] = h1;
        PsL[row][ksp * 16 + 16 + l15] = f2bf(p1 - bf2f(h1));
        float v = p0 + p1;
#pragma unroll
        for (int off = 1; off < 16; off <<= 1)
          v += __shfl_xor(v, off, 64);
        if (l15 == 0) red2[row][w >> 1] = v;
      }
    __syncthreads();  // B3
    if (tid < 64) l_s[tid] = l_s[tid] * al_s[tid] + red2[tid][0] + red2[tid][1];

    // ----------------- O = O*alpha + P @ V (3-term split) -----------------
    float alv[4][4];
#pragma unroll
    for (int qt = 0; qt < 4; ++qt)
#pragma unroll
      for (int r = 0; r < 4; ++r)
        alv[qt][r] = al_s[qt * 16 + quad * 4 + r];
#pragma unroll
    for (int qt = 0; qt < 4; ++qt)
#pragma unroll
      for (int nt = 0; nt < 8; ++nt)
#pragma unroll
        for (int r = 0; r < 4; ++r)
          Of[qt][nt][r] *= alv[qt][r];
#pragma unroll
    for (int ks = 0; ks < 2; ++ks) {
      bf16x8 Ph[4], Pl[4];
#pragma unroll
      for (int qt = 0; qt < 4; ++qt) {
        Ph[qt] = *(const bf16x8*)&PsH[qt * 16 + l15][ks * 32 + quad * 8];
        Pl[qt] = *(const bf16x8*)&PsL[qt * 16 + l15][ks * 32 + quad * 8];
      }
#pragma unroll
      for (int nt = 0; nt < 8; ++nt) {
        const size_t xo =
            ((size_t)(b * DIM + dbase + nt * 16 + l15)) * SEQ + k0 + ks * 32 + quad * 8;
        bf16x8 xh = *(const bf16x8*)(Xth + xo);
        bf16x8 xl = *(const bf16x8*)(Xtl + xo);
#pragma unroll
        for (int qt = 0; qt < 4; ++qt) {
          Of[qt][nt] = __builtin_amdgcn_mfma_f32_16x16x32_bf16(Ph[qt], xh, Of[qt][nt], 0, 0, 0);
          Of[qt][nt] = __builtin_amdgcn_mfma_f32_16x16x32_bf16(Pl[qt], xh, Of[qt][nt], 0, 0, 0);
          Of[qt][nt] = __builtin_amdgcn_mfma_f32_16x16x32_bf16(Ph[qt], xl, Of[qt][nt], 0, 0, 0);
        }
      }
    }
    // No trailing barrier: next tile's B1 protects Ps/al_s reuse.
  }

  __syncthreads();
  float inv[4][4];
#pragma unroll
  for (int qt = 0; qt < 4; ++qt)
#pragma unroll
    for (int r = 0; r < 4; ++r)
      inv[qt][r] = 1.0f / l_s[qt * 16 + quad * 4 + r];
#pragma unroll
  for (int qt = 0; qt < 4; ++qt)
#pragma unroll
    for (int r = 0; r < 4; ++r) {
      const size_t ro = ((size_t)(b * SEQ + q0 + qt * 16 + quad * 4 + r)) * DIM + dbase;
#pragma unroll
      for (int nt = 0; nt < 8; ++nt)
        out[ro + nt * 16 + l15] = Of[qt][nt][r] * inv[qt][r];
    }
}

// ---------------------------------------------------------------------------
extern "C" void kernel_launch(void* const* d_in, const int* in_sizes, int n_in,
                              void* d_out, int out_size, void* d_ws,
                              size_t ws_size, hipStream_t stream) {
  const float* x   = (const float*)d_in[0];
  const float* rot = (const float*)d_in[1];
  const float* ent = (const float*)d_in[2];
  float* out = (float*)d_out;

  const size_t NE = (size_t)BATCH * SEQ * DIM;  // 16,777,216
  unsigned short* qh  = (unsigned short*)d_ws;
  unsigned short* ql  = qh + NE;
  unsigned short* kh  = ql + NE;
  unsigned short* kl  = kh + NE;
  unsigned short* xth = kl + NE;
  unsigned short* xtl = xth + NE;
  unsigned short* wrh = xtl + NE;
  unsigned short* wrl = wrh + 262144;
  unsigned short* weh = wrl + 262144;
  unsigned short* wel = weh + 262144;
  // total: 6*NE + 4*262144 ushorts = ~194 MiB

  wt_split_kernel<<<128, 256, 0, stream>>>(rot, ent, wrh, wrl, weh, wel);
  xt_split_kernel<<<dim3(SEQ / 64, DIM / 64, BATCH), 256, 0, stream>>>(x, xth, xtl);
  proj_mfma<<<dim3(DIM / 64, BATCH * SEQ / 64), 256, 0, stream>>>(x, wrh, wrl, qh, ql);
  proj_mfma<<<dim3(DIM / 64, BATCH * SEQ / 64), 256, 0, stream>>>(x, weh, wel, kh, kl);
  attn_mfma<<<dim3(SEQ / 64, BATCH), 256, 0, stream>>>(qh, ql, kh, kl, xth, xtl, out);
}

// Round 4
// 1573.342 us; speedup vs baseline: 149.0828x; 2.0626x over previous
//
#include <hip/hip_runtime.h>

#define BATCH 8
#define SEQ   4096
#define DIM   512

typedef __attribute__((ext_vector_type(8))) short bf16x8;
typedef __attribute__((ext_vector_type(4))) float f32x4;

__device__ __forceinline__ unsigned short f2bf(float f) {
  unsigned int u = __float_as_uint(f);
  unsigned int r = (u + 0x7fffu + ((u >> 16) & 1u)) >> 16;
  return (unsigned short)r;
}
__device__ __forceinline__ float bf2f(unsigned short s) {
  return __uint_as_float(((unsigned int)s) << 16);
}

// ---------------------------------------------------------------------------
// Transpose + split weights: Wt[e][d] = W[d][e] (* scale for rotation).
// ---------------------------------------------------------------------------
__global__ __launch_bounds__(256) void wt_split_kernel(
    const float* __restrict__ rot, const float* __restrict__ ent,
    unsigned short* __restrict__ wrh, unsigned short* __restrict__ wrl,
    unsigned short* __restrict__ weh, unsigned short* __restrict__ wel) {
  const float scale = 0.04419417382415922f;  // 1/sqrt(512)
  int g = blockIdx.x * 256 + threadIdx.x;
  for (int idx = g; idx < 512 * 512; idx += 128 * 256) {
    int d = idx >> 9, e = idx & 511;
    size_t o = (size_t)e * 512 + d;
    float v = rot[idx] * scale;
    unsigned short h = f2bf(v);
    wrh[o] = h; wrl[o] = f2bf(v - bf2f(h));
    float v2 = ent[idx];
    unsigned short h2 = f2bf(v2);
    weh[o] = h2; wel[o] = f2bf(v2 - bf2f(h2));
  }
}

// ---------------------------------------------------------------------------
// Transpose x: Xt[b][d][n] = x[b][n][d], bf16 hi only (PV is single-term).
// ---------------------------------------------------------------------------
__global__ __launch_bounds__(256) void xt_split_kernel(
    const float* __restrict__ X, unsigned short* __restrict__ Th) {
  __shared__ float T[64][65];
  const int b = blockIdx.z, n0 = blockIdx.x * 64, d0 = blockIdx.y * 64;
  const int tid = threadIdx.x;
  for (int idx = tid; idx < 4096; idx += 256) {
    int r = idx >> 6, c = idx & 63;
    T[r][c] = X[((size_t)(b * SEQ + n0 + r)) * DIM + d0 + c];
  }
  __syncthreads();
  for (int idx = tid; idx < 4096; idx += 256) {
    int r = idx >> 6, c = idx & 63;  // r: d, c: n
    size_t o = ((size_t)(b * DIM + d0 + r)) * SEQ + n0 + c;
    Th[o] = f2bf(T[c][r]);
  }
}

// ---------------------------------------------------------------------------
// Fused projection: Q = X@rot*scale, K = X@ent via bf16-split MFMA (3 terms).
// X split to bf16 hi/lo once, used for both outputs.
// ---------------------------------------------------------------------------
__global__ __launch_bounds__(256, 2) void proj_both(
    const float* __restrict__ X,
    const unsigned short* __restrict__ wrh, const unsigned short* __restrict__ wrl,
    const unsigned short* __restrict__ weh, const unsigned short* __restrict__ wel,
    unsigned short* __restrict__ qh, unsigned short* __restrict__ ql,
    unsigned short* __restrict__ kh, unsigned short* __restrict__ kl) {
  const int tid = threadIdx.x;
  const int w = tid >> 6, lane = tid & 63, l15 = lane & 15, quad = lane >> 4;
  const int rowBase = blockIdx.y * 64 + (w & 1) * 32;
  const int colBase = blockIdx.x * 64 + (w >> 1) * 32;
  f32x4 qa[2][2] = {}, ka[2][2] = {};
  const float* xp[2];
  const unsigned short *rh[2], *rl[2], *eh[2], *el[2];
  xp[0] = X + (size_t)(rowBase + l15) * DIM + quad * 8;
  xp[1] = X + (size_t)(rowBase + 16 + l15) * DIM + quad * 8;
#pragma unroll
  for (int ni = 0; ni < 2; ++ni) {
    size_t o = (size_t)(colBase + ni * 16 + l15) * DIM + quad * 8;
    rh[ni] = wrh + o; rl[ni] = wrl + o; eh[ni] = weh + o; el[ni] = wel + o;
  }
  for (int d0 = 0; d0 < DIM; d0 += 32) {
    bf16x8 ah[2], al[2];
#pragma unroll
    for (int mi = 0; mi < 2; ++mi) {
      const float* p = xp[mi] + d0;
#pragma unroll
      for (int e = 0; e < 8; ++e) {
        float v = p[e];
        unsigned short h = f2bf(v);
        ah[mi][e] = (short)h;
        al[mi][e] = (short)f2bf(v - bf2f(h));
      }
    }
#pragma unroll
    for (int ni = 0; ni < 2; ++ni) {
      bf16x8 bh = *(const bf16x8*)(rh[ni] + d0);
      bf16x8 bl = *(const bf16x8*)(rl[ni] + d0);
      bf16x8 ch = *(const bf16x8*)(eh[ni] + d0);
      bf16x8 cl = *(const bf16x8*)(el[ni] + d0);
#pragma unroll
      for (int mi = 0; mi < 2; ++mi) {
        qa[mi][ni] = __builtin_amdgcn_mfma_f32_16x16x32_bf16(ah[mi], bh, qa[mi][ni], 0, 0, 0);
        qa[mi][ni] = __builtin_amdgcn_mfma_f32_16x16x32_bf16(ah[mi], bl, qa[mi][ni], 0, 0, 0);
        qa[mi][ni] = __builtin_amdgcn_mfma_f32_16x16x32_bf16(al[mi], bh, qa[mi][ni], 0, 0, 0);
        ka[mi][ni] = __builtin_amdgcn_mfma_f32_16x16x32_bf16(ah[mi], ch, ka[mi][ni], 0, 0, 0);
        ka[mi][ni] = __builtin_amdgcn_mfma_f32_16x16x32_bf16(ah[mi], cl, ka[mi][ni], 0, 0, 0);
        ka[mi][ni] = __builtin_amdgcn_mfma_f32_16x16x32_bf16(al[mi], ch, ka[mi][ni], 0, 0, 0);
      }
    }
  }
#pragma unroll
  for (int mi = 0; mi < 2; ++mi)
#pragma unroll
    for (int ni = 0; ni < 2; ++ni)
#pragma unroll
      for (int r = 0; r < 4; ++r) {
        int row = rowBase + mi * 16 + quad * 4 + r;
        int col = colBase + ni * 16 + l15;
        size_t o = (size_t)row * DIM + col;
        float v = qa[mi][ni][r];
        unsigned short h = f2bf(v);
        qh[o] = h; ql[o] = f2bf(v - bf2f(h));
        float v2 = ka[mi][ni][r];
        unsigned short h2 = f2bf(v2);
        kh[o] = h2; kl[o] = f2bf(v2 - bf2f(h2));
      }
}

// ---------------------------------------------------------------------------
// Flash attention, BQ=64, BK=64, 4 waves.
// S-stage: Q/K hi+lo staged to LDS in 32-d chunks, double-buffered,
// XOR-swizzled (conflict-free), MFMA reads via ds_read_b128.
// PV: single-term (Ph * xh), X frags per-lane from global.
// Split-K via gridDim.z: partial (O, m, l) to workspace, merged by merge_kernel.
// ---------------------------------------------------------------------------
__global__ __launch_bounds__(256, 2) void attn_mfma(
    const unsigned short* __restrict__ Qh, const unsigned short* __restrict__ Ql,
    const unsigned short* __restrict__ Kh, const unsigned short* __restrict__ Kl,
    const unsigned short* __restrict__ Xth, float* __restrict__ out,
    float* __restrict__ Opart, float* __restrict__ Mp, float* __restrict__ Lp) {
  // stage[buf][plane][64 rows * 32 bf16]; planes: 0=Qh 1=Ql 2=Kh 3=Kl
  __shared__ short stage[2][4][2048];          // 32 KiB
  __shared__ unsigned short PsH[64][72];       // 9 KiB
  __shared__ float red1[64][2], red2[64][2];
  __shared__ float m_s[64], l_s[64], al_s[64];

  const int tid = threadIdx.x;
  const int w = tid >> 6, lane = tid & 63, l15 = lane & 15, quad = lane >> 4;
  const int b = blockIdx.y, q0 = blockIdx.x * 64;
  const int qsp = (w & 1) * 2, ksp = (w >> 1) * 2;
  const int dbase = w * 128;
  const int ktiles = (SEQ / 64) / gridDim.z;
  const int kbase = blockIdx.z * ktiles * 64;

  if (tid < 64) { m_s[tid] = -3.0e38f; l_s[tid] = 0.0f; }
  __syncthreads();

  f32x4 Of[4][8] = {};

  // staging geometry (per wave stages one plane): lane -> (r = i*16 + lane/4,
  // cm = lane&3), logical 16B-block clog = cm ^ (r&3).
  const int sr = lane >> 2, scm = lane & 3;
  const unsigned short* qsrc = ((w & 1) ? Ql : Qh) + (size_t)(b * SEQ + q0) * DIM;
  const unsigned short* ksrcb = ((w & 1) ? Kl : Kh) + (size_t)b * SEQ * DIM;
  const bool isQ = (w < 2);

  for (int t = 0; t < ktiles; ++t) {
    const int k0 = kbase + t * 64;
    const unsigned short* base = isQ ? qsrc : (ksrcb + (size_t)k0 * DIM);

    // ---- stage chunk 0 ----
    {
      bf16x8 g[4];
#pragma unroll
      for (int i = 0; i < 4; ++i) {
        int r = i * 16 + sr, clog = scm ^ (r & 3);
        g[i] = *(const bf16x8*)(base + (size_t)r * DIM + clog * 8);
      }
#pragma unroll
      for (int i = 0; i < 4; ++i) {
        int r = i * 16 + sr;
        *(bf16x8*)&stage[0][w][r * 32 + scm * 8] = g[i];
      }
    }
    __syncthreads();

    // ---- S = Q K^T over 16 chunks of 32-d, double-buffered ----
    f32x4 sa[2][2] = {};
    for (int c = 0; c < 16; ++c) {
      const int bsel = c & 1;
      bf16x8 g[4];
      if (c < 15) {
        const int d0 = (c + 1) * 32;
#pragma unroll
        for (int i = 0; i < 4; ++i) {
          int r = i * 16 + sr, clog = scm ^ (r & 3);
          g[i] = *(const bf16x8*)(base + (size_t)r * DIM + d0 + clog * 8);
        }
      }
      // fragment reads (swizzled): row = sub*16+l15, block = quad ^ (l15&3)
      const int cq = (quad ^ (l15 & 3)) * 8;
      bf16x8 a0h = *(const bf16x8*)&stage[bsel][0][((qsp + 0) * 16 + l15) * 32 + cq];
      bf16x8 a0l = *(const bf16x8*)&stage[bsel][1][((qsp + 0) * 16 + l15) * 32 + cq];
      bf16x8 a1h = *(const bf16x8*)&stage[bsel][0][((qsp + 1) * 16 + l15) * 32 + cq];
      bf16x8 a1l = *(const bf16x8*)&stage[bsel][1][((qsp + 1) * 16 + l15) * 32 + cq];
      bf16x8 b0h = *(const bf16x8*)&stage[bsel][2][((ksp + 0) * 16 + l15) * 32 + cq];
      bf16x8 b0l = *(const bf16x8*)&stage[bsel][3][((ksp + 0) * 16 + l15) * 32 + cq];
      bf16x8 b1h = *(const bf16x8*)&stage[bsel][2][((ksp + 1) * 16 + l15) * 32 + cq];
      bf16x8 b1l = *(const bf16x8*)&stage[bsel][3][((ksp + 1) * 16 + l15) * 32 + cq];
      sa[0][0] = __builtin_amdgcn_mfma_f32_16x16x32_bf16(a0h, b0h, sa[0][0], 0, 0, 0);
      sa[0][0] = __builtin_amdgcn_mfma_f32_16x16x32_bf16(a0h, b0l, sa[0][0], 0, 0, 0);
      sa[0][0] = __builtin_amdgcn_mfma_f32_16x16x32_bf16(a0l, b0h, sa[0][0], 0, 0, 0);
      sa[0][1] = __builtin_amdgcn_mfma_f32_16x16x32_bf16(a0h, b1h, sa[0][1], 0, 0, 0);
      sa[0][1] = __builtin_amdgcn_mfma_f32_16x16x32_bf16(a0h, b1l, sa[0][1], 0, 0, 0);
      sa[0][1] = __builtin_amdgcn_mfma_f32_16x16x32_bf16(a0l, b1h, sa[0][1], 0, 0, 0);
      sa[1][0] = __builtin_amdgcn_mfma_f32_16x16x32_bf16(a1h, b0h, sa[1][0], 0, 0, 0);
      sa[1][0] = __builtin_amdgcn_mfma_f32_16x16x32_bf16(a1h, b0l, sa[1][0], 0, 0, 0);
      sa[1][0] = __builtin_amdgcn_mfma_f32_16x16x32_bf16(a1l, b0h, sa[1][0], 0, 0, 0);
      sa[1][1] = __builtin_amdgcn_mfma_f32_16x16x32_bf16(a1h, b1h, sa[1][1], 0, 0, 0);
      sa[1][1] = __builtin_amdgcn_mfma_f32_16x16x32_bf16(a1h, b1l, sa[1][1], 0, 0, 0);
      sa[1][1] = __builtin_amdgcn_mfma_f32_16x16x32_bf16(a1l, b1h, sa[1][1], 0, 0, 0);
      if (c < 15) {
#pragma unroll
        for (int i = 0; i < 4; ++i) {
          int r = i * 16 + sr;
          *(bf16x8*)&stage[1 - bsel][w][r * 32 + scm * 8] = g[i];
        }
      }
      __syncthreads();
    }

    // ---- row-max partials ----
    float pm[2][4];
#pragma unroll
    for (int qi = 0; qi < 2; ++qi)
#pragma unroll
      for (int r = 0; r < 4; ++r) {
        float v = fmaxf(sa[qi][0][r], sa[qi][1][r]);
#pragma unroll
        for (int off = 1; off < 16; off <<= 1)
          v = fmaxf(v, __shfl_xor(v, off, 64));
        pm[qi][r] = v;
      }
    if (l15 == 0) {
#pragma unroll
      for (int qi = 0; qi < 2; ++qi)
#pragma unroll
        for (int r = 0; r < 4; ++r)
          red1[(qsp + qi) * 16 + quad * 4 + r][w >> 1] = pm[qi][r];
    }
    __syncthreads();  // B1
    if (tid < 64) {
      float mo = m_s[tid];
      float mn = fmaxf(mo, fmaxf(red1[tid][0], red1[tid][1]));
      m_s[tid] = mn;
      al_s[tid] = __expf(mo - mn);
    }
    __syncthreads();  // B2

    // ---- exp + P(hi) to LDS + row sums ----
#pragma unroll
    for (int qi = 0; qi < 2; ++qi)
#pragma unroll
      for (int r = 0; r < 4; ++r) {
        const int row = (qsp + qi) * 16 + quad * 4 + r;
        const float m = m_s[row];
        float p0 = __expf(sa[qi][0][r] - m);
        float p1 = __expf(sa[qi][1][r] - m);
        PsH[row][ksp * 16 + l15] = f2bf(p0);
        PsH[row][ksp * 16 + 16 + l15] = f2bf(p1);
        float v = p0 + p1;
#pragma unroll
        for (int off = 1; off < 16; off <<= 1)
          v += __shfl_xor(v, off, 64);
        if (l15 == 0) red2[row][w >> 1] = v;
      }
    __syncthreads();  // B3
    if (tid < 64) l_s[tid] = l_s[tid] * al_s[tid] + red2[tid][0] + red2[tid][1];

    // ---- O = O*alpha + P @ x (single-term) ----
    float alv[4][4];
#pragma unroll
    for (int qt = 0; qt < 4; ++qt)
#pragma unroll
      for (int r = 0; r < 4; ++r)
        alv[qt][r] = al_s[qt * 16 + quad * 4 + r];
#pragma unroll
    for (int qt = 0; qt < 4; ++qt)
#pragma unroll
      for (int nt = 0; nt < 8; ++nt)
#pragma unroll
        for (int r = 0; r < 4; ++r)
          Of[qt][nt][r] *= alv[qt][r];
#pragma unroll
    for (int ks = 0; ks < 2; ++ks) {
      bf16x8 Ph[4];
#pragma unroll
      for (int qt = 0; qt < 4; ++qt)
        Ph[qt] = *(const bf16x8*)&PsH[qt * 16 + l15][ks * 32 + quad * 8];
      bf16x8 xf[8];
#pragma unroll
      for (int nt = 0; nt < 8; ++nt) {
        const size_t xo =
            ((size_t)(b * DIM + dbase + nt * 16 + l15)) * SEQ + k0 + ks * 32 + quad * 8;
        xf[nt] = *(const bf16x8*)(Xth + xo);
      }
#pragma unroll
      for (int nt = 0; nt < 8; ++nt)
#pragma unroll
        for (int qt = 0; qt < 4; ++qt)
          Of[qt][nt] = __builtin_amdgcn_mfma_f32_16x16x32_bf16(Ph[qt], xf[nt], Of[qt][nt], 0, 0, 0);
    }
    __syncthreads();  // protect PsH / al_s / stage reuse next tile
  }

  if (gridDim.z == 1) {
    float inv[4][4];
#pragma unroll
    for (int qt = 0; qt < 4; ++qt)
#pragma unroll
      for (int r = 0; r < 4; ++r)
        inv[qt][r] = 1.0f / l_s[qt * 16 + quad * 4 + r];
#pragma unroll
    for (int qt = 0; qt < 4; ++qt)
#pragma unroll
      for (int r = 0; r < 4; ++r) {
        const size_t ro = ((size_t)(b * SEQ + q0 + qt * 16 + quad * 4 + r)) * DIM + dbase;
#pragma unroll
        for (int nt = 0; nt < 8; ++nt)
          out[ro + nt * 16 + l15] = Of[qt][nt][r] * inv[qt][r];
      }
  } else {
    const size_t NE = (size_t)BATCH * SEQ * DIM;
    float* Ob = Opart + (size_t)blockIdx.z * NE;
#pragma unroll
    for (int qt = 0; qt < 4; ++qt)
#pragma unroll
      for (int r = 0; r < 4; ++r) {
        const size_t ro = ((size_t)(b * SEQ + q0 + qt * 16 + quad * 4 + r)) * DIM + dbase;
#pragma unroll
        for (int nt = 0; nt < 8; ++nt)
          Ob[ro + nt * 16 + l15] = Of[qt][nt][r];
      }
    if (tid < 64) {
      size_t ri = (size_t)blockIdx.z * (BATCH * SEQ) + (size_t)b * SEQ + q0 + tid;
      Mp[ri] = m_s[tid];
      Lp[ri] = l_s[tid];
    }
  }
}

// ---------------------------------------------------------------------------
// Merge two split-K partials: out = (a0*O0 + a1*O1) / (a0*l0 + a1*l1).
// ---------------------------------------------------------------------------
__global__ __launch_bounds__(256) void merge_kernel(
    const float* __restrict__ Op, const float* __restrict__ Mp,
    const float* __restrict__ Lp, float* __restrict__ out) {
  const size_t NE = (size_t)BATCH * SEQ * DIM;
  const int NR = BATCH * SEQ;
  size_t i4 = (size_t)blockIdx.x * 256 + threadIdx.x;
  size_t e = i4 * 4;
  int row = (int)(e >> 9);
  float m0 = Mp[row], m1 = Mp[NR + row];
  float l0 = Lp[row], l1 = Lp[NR + row];
  float m = fmaxf(m0, m1);
  float a0 = __expf(m0 - m), a1 = __expf(m1 - m);
  float inv = 1.0f / (a0 * l0 + a1 * l1);
  float4 o0 = *(const float4*)(Op + e);
  float4 o1 = *(const float4*)(Op + NE + e);
  float4 r;
  r.x = (a0 * o0.x + a1 * o1.x) * inv;
  r.y = (a0 * o0.y + a1 * o1.y) * inv;
  r.z = (a0 * o0.z + a1 * o1.z) * inv;
  r.w = (a0 * o0.w + a1 * o1.w) * inv;
  *(float4*)(out + e) = r;
}

// ---------------------------------------------------------------------------
extern "C" void kernel_launch(void* const* d_in, const int* in_sizes, int n_in,
                              void* d_out, int out_size, void* d_ws,
                              size_t ws_size, hipStream_t stream) {
  const float* x   = (const float*)d_in[0];
  const float* rot = (const float*)d_in[1];
  const float* ent = (const float*)d_in[2];
  float* out = (float*)d_out;

  const size_t NE = (size_t)BATCH * SEQ * DIM;  // 16,777,216
  unsigned short* qh  = (unsigned short*)d_ws;
  unsigned short* ql  = qh + NE;
  unsigned short* kh  = ql + NE;
  unsigned short* kl  = kh + NE;
  unsigned short* xth = kl + NE;
  unsigned short* wrh = xth + NE;
  unsigned short* wrl = wrh + 262144;
  unsigned short* weh = wrl + 262144;
  unsigned short* wel = weh + 262144;
  float* Opart = (float*)(wel + 262144);     // 2*NE floats if splits==2
  float* Mp    = Opart + 2 * NE;             // 2*32768
  float* Lp    = Mp + 2 * (BATCH * SEQ);

  const size_t need2 =
      (5 * NE + 4 * 262144) * sizeof(unsigned short) +
      (2 * NE + 4 * (size_t)(BATCH * SEQ)) * sizeof(float);
  const int splits = (ws_size >= need2) ? 2 : 1;

  wt_split_kernel<<<128, 256, 0, stream>>>(rot, ent, wrh, wrl, weh, wel);
  xt_split_kernel<<<dim3(SEQ / 64, DIM / 64, BATCH), 256, 0, stream>>>(x, xth);
  proj_both<<<dim3(DIM / 64, BATCH * SEQ / 64), 256, 0, stream>>>(
      x, wrh, wrl, weh, wel, qh, ql, kh, kl);

  attn_mfma<<<dim3(SEQ / 64, BATCH, splits), 256, 0, stream>>>(
      qh, ql, kh, kl, xth, out, Opart, Mp, Lp);
  if (splits == 2) {
    merge_kernel<<<(unsigned)(NE / 1024), 256, 0, stream>>>(Opart, Mp, Lp, out);
  }
}